// Round 3
// baseline (302.103 us; speedup 1.0000x reference)
//
#include <hip/hip_runtime.h>

#define IN_F 128
#define C1 64
#define NG 128
#define CAT 192

typedef unsigned short u16;
typedef unsigned int u32;

__device__ inline u16 f2bf(float f) {
  u32 u = __float_as_uint(f);
  u = (u + 0x7FFFu + ((u >> 16) & 1u)) >> 16;   // RTNE
  return (u16)u;
}
__device__ inline float bf2f(u16 h) { return __uint_as_float(((u32)h) << 16); }

// ================= CSR build (locality-clean) =================
// digit = dst >> 9  (512 nodes per digit)

__global__ __launch_bounds__(256) void hist_k(const int* __restrict__ dst, int e,
                                              int* __restrict__ ghist, int ndig) {
  __shared__ int h[256];
  int t = threadIdx.x;
  h[t] = 0;
  __syncthreads();
  int base = blockIdx.x * 4096;
  #pragma unroll
  for (int i = 0; i < 16; i++) {
    int j = base + t + i * 256;
    if (j < e) atomicAdd(&h[dst[j] >> 9], 1);
  }
  __syncthreads();
  if (t < ndig && h[t] > 0) atomicAdd(&ghist[t], h[t]);
}

__global__ void dscan_k(const int* __restrict__ ghist, int* __restrict__ dstart,
                        int* __restrict__ gcur, int ndig, int e) {
  __shared__ int lds[256];
  int t = threadIdx.x;
  int v = (t < ndig) ? ghist[t] : 0;
  lds[t] = v;
  __syncthreads();
  #pragma unroll
  for (int off = 1; off < 256; off <<= 1) {
    int x = lds[t] + ((t >= off) ? lds[t - off] : 0);
    __syncthreads();
    lds[t] = x;
    __syncthreads();
  }
  int excl = lds[t] - v;
  if (t < ndig) { dstart[t] = excl; gcur[t] = excl; }
  if (t == 0) dstart[ndig] = e;
}

__global__ __launch_bounds__(256) void stage_k(const int* __restrict__ src,
                                               const int* __restrict__ dst, int e,
                                               int* __restrict__ gcur,
                                               int2* __restrict__ stage, int ndig) {
  __shared__ int h[256];
  __shared__ int cur[256];
  int t = threadIdx.x;
  h[t] = 0;
  __syncthreads();
  int base = blockIdx.x * 4096;
  int mys[16], myd[16];
  #pragma unroll
  for (int i = 0; i < 16; i++) {
    int j = base + t + i * 256;
    if (j < e) {
      mys[i] = src[j];
      myd[i] = dst[j];
      atomicAdd(&h[myd[i] >> 9], 1);
    } else {
      myd[i] = -1;
    }
  }
  __syncthreads();
  int cnt = h[t];
  __syncthreads();
  int gbase = 0;
  if (t < ndig && cnt > 0) gbase = atomicAdd(&gcur[t], cnt);
  h[t] = gbase;
  cur[t] = 0;
  __syncthreads();
  #pragma unroll
  for (int i = 0; i < 16; i++) {
    if (myd[i] >= 0) {
      int d = myd[i] >> 9;
      int r = atomicAdd(&cur[d], 1);
      stage[h[d] + r] = make_int2(mys[i], myd[i]);
    }
  }
}

__global__ __launch_bounds__(256) void csr_k(const int2* __restrict__ stage,
                                             const int* __restrict__ dstart,
                                             int* __restrict__ rowptr,
                                             int* __restrict__ counts,
                                             float* __restrict__ dinv,
                                             int* __restrict__ csr, int n) {
  __shared__ int hc[512];
  __shared__ int hb[512];
  __shared__ int cu[512];
  __shared__ int sc[256];
  int dg = blockIdx.x;
  int t = threadIdx.x;
  int n0 = dg * 512;
  int nloc = min(n - n0, 512);
  int e0 = dstart[dg], e1 = dstart[dg + 1];
  hc[t] = 0; hc[t + 256] = 0;
  __syncthreads();
  for (int j = e0 + t; j < e1; j += 256) atomicAdd(&hc[stage[j].y - n0], 1);
  __syncthreads();
  int a0 = hc[2 * t], a1 = hc[2 * t + 1];
  int s = a0 + a1;
  sc[t] = s;
  __syncthreads();
  #pragma unroll
  for (int off = 1; off < 256; off <<= 1) {
    int x = sc[t] + ((t >= off) ? sc[t - off] : 0);
    __syncthreads();
    sc[t] = x;
    __syncthreads();
  }
  int excl = sc[t] - s;
  hb[2 * t] = excl;
  hb[2 * t + 1] = excl + a0;
  cu[2 * t] = 0; cu[2 * t + 1] = 0;
  __syncthreads();
  for (int i = t; i < nloc; i += 256) {
    int node = n0 + i;
    rowptr[node] = e0 + hb[i];
    counts[node] = hc[i];
    dinv[node] = rsqrtf((float)hc[i] + 1.0f);
  }
  __syncthreads();
  for (int j = e0 + t; j < e1; j += 256) {
    int2 p = stage[j];
    int li = p.y - n0;
    int r = atomicAdd(&cu[li], 1);
    csr[e0 + hb[li] + r] = p.x;
  }
}

// ================= dense GEMM  Y[N,64](bf16) = X[N,K] @ W[K,64] =================
// IN_BF16: X is bf16 (ushort); else f32.

template <int K, bool IN_BF16>
__global__ __launch_bounds__(256) void gemm_k(const void* __restrict__ Xv,
                                              const float* __restrict__ W,
                                              u16* __restrict__ Y, int n) {
  __shared__ float XT[32][68];
  __shared__ float Ws[32][64];
  int t = threadIdx.x;
  int row0 = blockIdx.x * 64;
  int tx = t & 15, ty = t >> 4;
  float acc[4][4] = {};
  for (int kt = 0; kt < K; kt += 32) {
    {
      int r = t >> 2;
      int q = t & 3;
      int gr = row0 + r;
      #pragma unroll
      for (int h = 0; h < 2; h++) {
        int k0 = q * 8 + h * 4;
        float v0 = 0.f, v1 = 0.f, v2 = 0.f, v3 = 0.f;
        if (gr < n) {
          if (IN_BF16) {
            const ushort4 xv = *(const ushort4*)((const u16*)Xv + (size_t)gr * K + kt + k0);
            v0 = bf2f(xv.x); v1 = bf2f(xv.y); v2 = bf2f(xv.z); v3 = bf2f(xv.w);
          } else {
            const float4 xv = *(const float4*)((const float*)Xv + (size_t)gr * K + kt + k0);
            v0 = xv.x; v1 = xv.y; v2 = xv.z; v3 = xv.w;
          }
        }
        XT[k0 + 0][r] = v0;
        XT[k0 + 1][r] = v1;
        XT[k0 + 2][r] = v2;
        XT[k0 + 3][r] = v3;
      }
    }
    {
      int k = t >> 3;
      int q = t & 7;
      *(float4*)&Ws[k][q * 8 + 0] = *(const float4*)(W + (size_t)(kt + k) * 64 + q * 8);
      *(float4*)&Ws[k][q * 8 + 4] = *(const float4*)(W + (size_t)(kt + k) * 64 + q * 8 + 4);
    }
    __syncthreads();
    #pragma unroll
    for (int k = 0; k < 32; k++) {
      float4 xv = *(const float4*)&XT[k][ty * 4];
      float4 wv = *(const float4*)&Ws[k][tx * 4];
      float xa[4] = {xv.x, xv.y, xv.z, xv.w};
      float wa[4] = {wv.x, wv.y, wv.z, wv.w};
      #pragma unroll
      for (int i = 0; i < 4; i++)
        #pragma unroll
        for (int j = 0; j < 4; j++)
          acc[i][j] += xa[i] * wa[j];
    }
    __syncthreads();
  }
  #pragma unroll
  for (int i = 0; i < 4; i++) {
    int gr = row0 + ty * 4 + i;
    if (gr < n) {
      ushort4 o;
      o.x = f2bf(acc[i][0]); o.y = f2bf(acc[i][1]);
      o.z = f2bf(acc[i][2]); o.w = f2bf(acc[i][3]);
      *(ushort4*)(Y + (size_t)gr * 64 + tx * 4) = o;
    }
  }
}

// ================= edge aggregation (bf16 gather) + bias + relu =================

__global__ __launch_bounds__(256) void gather_k(const u16* __restrict__ xw,
                                                u16* __restrict__ hout,
                                                const int* __restrict__ rowptr,
                                                const int* __restrict__ counts,
                                                const int* __restrict__ csr,
                                                const float* __restrict__ dinv,
                                                const float* __restrict__ bias, int n) {
  int idx = blockIdx.x * 256 + threadIdx.x;
  int nid = idx >> 4;
  int lane = idx & 15;
  if (nid >= n) return;
  float di = dinv[nid];
  ushort4 a = *(const ushort4*)(xw + (size_t)nid * 64 + lane * 4);
  float sc = di * di;
  float ax = bf2f(a.x) * sc, ay = bf2f(a.y) * sc, az = bf2f(a.z) * sc, aw = bf2f(a.w) * sc;
  int st = rowptr[nid];
  int cn = counts[nid];
  for (int i = 0; i < cn; i++) {
    int s = csr[st + i];
    float wgt = dinv[s] * di;
    ushort4 xs = *(const ushort4*)(xw + (size_t)s * 64 + lane * 4);
    ax += bf2f(xs.x) * wgt;
    ay += bf2f(xs.y) * wgt;
    az += bf2f(xs.z) * wgt;
    aw += bf2f(xs.w) * wgt;
  }
  float4 b = *(const float4*)(bias + lane * 4);
  ax = fmaxf(ax + b.x, 0.f);
  ay = fmaxf(ay + b.y, 0.f);
  az = fmaxf(az + b.z, 0.f);
  aw = fmaxf(aw + b.w, 0.f);
  ushort4 o;
  o.x = f2bf(ax); o.y = f2bf(ay); o.z = f2bf(az); o.w = f2bf(aw);
  *(ushort4*)(hout + (size_t)nid * 64 + lane * 4) = o;
}

// ================= pooling + head =================

__global__ void bounds_k(const int* __restrict__ batch, int* __restrict__ startg, int n) {
  int t = threadIdx.x;
  if (t <= NG) {
    int lo = 0, hi = n;
    while (lo < hi) {
      int mid = (lo + hi) >> 1;
      if (batch[mid] < t) lo = mid + 1; else hi = mid;
    }
    startg[t] = lo;
  }
}

__global__ __launch_bounds__(1024) void pool_k(const u16* __restrict__ h,
                                               const int* __restrict__ startg,
                                               float* __restrict__ xcat) {
  int g = blockIdx.x;
  int s = startg[g], e = startg[g + 1];
  int lane = threadIdx.x & 63;
  int wv = threadIdx.x >> 6;
  float sum = 0.f, mx = 0.f;
  for (int nn = s + wv; nn < e; nn += 16) {
    float v = bf2f(h[(size_t)nn * 64 + lane]);
    sum += v;
    mx = fmaxf(mx, v);
  }
  __shared__ float lsum[16][64];
  __shared__ float lmax[16][64];
  lsum[wv][lane] = sum;
  lmax[wv][lane] = mx;
  __syncthreads();
  if (wv == 0) {
    #pragma unroll
    for (int i = 1; i < 16; i++) {
      sum += lsum[i][lane];
      mx = fmaxf(mx, lmax[i][lane]);
    }
    int cnt = e - s;
    xcat[g * CAT + lane]       = sum;
    xcat[g * CAT + 64 + lane]  = sum / fmaxf((float)cnt, 1.0f);
    xcat[g * CAT + 128 + lane] = mx;
  }
}

__global__ void head_k(const float* __restrict__ xcat, const float* __restrict__ Wlin,
                       const float* __restrict__ blin, float* __restrict__ out) {
  int t = threadIdx.x;
  int g = t >> 1, o = t & 1;
  float acc = blin[o];
  #pragma unroll 8
  for (int k = 0; k < CAT; k++) acc += xcat[g * CAT + k] * Wlin[k * 2 + o];
  out[g * 2 + o] = acc;
}

// ================= launch =================

extern "C" void kernel_launch(void* const* d_in, const int* in_sizes, int n_in,
                              void* d_out, int out_size, void* d_ws, size_t ws_size,
                              hipStream_t stream) {
  const float* x    = (const float*)d_in[0];
  const float* W1   = (const float*)d_in[1];
  const float* b1   = (const float*)d_in[2];
  const float* W2   = (const float*)d_in[3];
  const float* b2   = (const float*)d_in[4];
  const float* Wlin = (const float*)d_in[5];
  const float* blin = (const float*)d_in[6];
  const int*   ei   = (const int*)d_in[7];
  const int*   batch= (const int*)d_in[8];

  const int N = in_sizes[0] / IN_F;      // 100000
  const int E = in_sizes[7] / 2;         // 1600000
  const int* src = ei;
  const int* dst = ei + E;
  const int ndig = (N + 511) >> 9;       // 196
  const int nbE  = (E + 4095) / 4096;    // 391

  char* w = (char*)d_ws;
  auto alloc = [&](size_t bytes) {
    void* p = (void*)w;
    w += (bytes + 255) & ~(size_t)255;
    return p;
  };
  int*   rowptr = (int*)alloc((size_t)N * 4);
  int*   counts = (int*)alloc((size_t)N * 4);
  float* dinv   = (float*)alloc((size_t)N * 4);
  int*   csr    = (int*)alloc((size_t)E * 4);
  int*   ghist  = (int*)alloc(256 * 4);
  int*   dstart = (int*)alloc(260 * 4);
  int*   gcur   = (int*)alloc(256 * 4);
  int*   startg = (int*)alloc((NG + 2) * 4);
  u16*   bufA   = (u16*)alloc((size_t)N * 64 * 2);   // bf16 feature buffers
  u16*   bufB   = (u16*)alloc((size_t)N * 64 * 2);
  int2*  stage  = (int2*)alloc((size_t)E * 8);       // dedicated (dead after csr_k)

  float* xcat = (float*)d_out;
  float* outh = (float*)d_out + NG * CAT;

  hipMemsetAsync(ghist, 0, 256 * 4, stream);
  hist_k  <<<nbE, 256, 0, stream>>>(dst, E, ghist, ndig);
  dscan_k <<<1, 256, 0, stream>>>(ghist, dstart, gcur, ndig, E);
  stage_k <<<nbE, 256, 0, stream>>>(src, dst, E, gcur, stage, ndig);
  csr_k   <<<ndig, 256, 0, stream>>>(stage, dstart, rowptr, counts, dinv, csr, N);

  // layer 1
  gemm_k<IN_F, false> <<<(N + 63) / 64, 256, 0, stream>>>(x, W1, bufA, N);
  gather_k <<<(N * 16 + 255) / 256, 256, 0, stream>>>(bufA, bufB, rowptr, counts, csr, dinv, b1, N);

  // layer 2
  gemm_k<C1, true> <<<(N + 63) / 64, 256, 0, stream>>>(bufB, W2, bufA, N);
  gather_k <<<(N * 16 + 255) / 256, 256, 0, stream>>>(bufA, bufB, rowptr, counts, csr, dinv, b2, N);

  // pooling + head
  bounds_k <<<1, 256, 0, stream>>>(batch, startg, N);
  pool_k <<<NG, 1024, 0, stream>>>(bufB, startg, xcat);
  head_k <<<1, 256, 0, stream>>>(xcat, Wlin, blin, outh);
}

// Round 4
// 213.816 us; speedup vs baseline: 1.4129x; 1.4129x over previous
//
#include <hip/hip_runtime.h>

#define IN_F 128
#define C1 64
#define NG 128
#define CAT 192

typedef unsigned short u16;
typedef unsigned int u32;

__device__ inline u16 f2bf(float f) {
  u32 u = __float_as_uint(f);
  u = (u + 0x7FFFu + ((u >> 16) & 1u)) >> 16;   // RTNE
  return (u16)u;
}
__device__ inline float bf2f(u16 h) { return __uint_as_float(((u32)h) << 16); }
__device__ inline float bflo(u32 p) { return __uint_as_float(p << 16); }
__device__ inline float bfhi(u32 p) { return __uint_as_float(p & 0xFFFF0000u); }

// ================= CSR build (locality-clean) =================
// digit = dst >> 9  (512 nodes per digit)

__global__ __launch_bounds__(256) void hist_k(const int* __restrict__ dst, int e,
                                              int* __restrict__ ghist, int ndig) {
  __shared__ int h[256];
  int t = threadIdx.x;
  h[t] = 0;
  __syncthreads();
  int base = blockIdx.x * 4096;
  #pragma unroll
  for (int i = 0; i < 16; i++) {
    int j = base + t + i * 256;
    if (j < e) atomicAdd(&h[dst[j] >> 9], 1);
  }
  __syncthreads();
  if (t < ndig && h[t] > 0) atomicAdd(&ghist[t], h[t]);
}

__global__ void dscan_k(const int* __restrict__ ghist, int* __restrict__ dstart,
                        int* __restrict__ gcur, int ndig, int e) {
  __shared__ int lds[256];
  int t = threadIdx.x;
  int v = (t < ndig) ? ghist[t] : 0;
  lds[t] = v;
  __syncthreads();
  #pragma unroll
  for (int off = 1; off < 256; off <<= 1) {
    int x = lds[t] + ((t >= off) ? lds[t - off] : 0);
    __syncthreads();
    lds[t] = x;
    __syncthreads();
  }
  int excl = lds[t] - v;
  if (t < ndig) { dstart[t] = excl; gcur[t] = excl; }
  if (t == 0) dstart[ndig] = e;
}

__global__ __launch_bounds__(256) void stage_k(const int* __restrict__ src,
                                               const int* __restrict__ dst, int e,
                                               int* __restrict__ gcur,
                                               int2* __restrict__ stage, int ndig) {
  __shared__ int h[256];
  __shared__ int cur[256];
  int t = threadIdx.x;
  h[t] = 0;
  __syncthreads();
  int base = blockIdx.x * 4096;
  int mys[16], myd[16];
  #pragma unroll
  for (int i = 0; i < 16; i++) {
    int j = base + t + i * 256;
    if (j < e) {
      mys[i] = src[j];
      myd[i] = dst[j];
      atomicAdd(&h[myd[i] >> 9], 1);
    } else {
      myd[i] = -1;
    }
  }
  __syncthreads();
  int cnt = h[t];
  __syncthreads();
  int gbase = 0;
  if (t < ndig && cnt > 0) gbase = atomicAdd(&gcur[t], cnt);
  h[t] = gbase;
  cur[t] = 0;
  __syncthreads();
  #pragma unroll
  for (int i = 0; i < 16; i++) {
    if (myd[i] >= 0) {
      int d = myd[i] >> 9;
      int r = atomicAdd(&cur[d], 1);
      stage[h[d] + r] = make_int2(mys[i], myd[i]);
    }
  }
}

__global__ __launch_bounds__(256) void csr_k(const int2* __restrict__ stage,
                                             const int* __restrict__ dstart,
                                             int* __restrict__ rowptr,
                                             int* __restrict__ counts,
                                             float* __restrict__ dinv,
                                             int* __restrict__ csr, int n) {
  __shared__ int hc[512];
  __shared__ int hb[512];
  __shared__ int cu[512];
  __shared__ int sc[256];
  int dg = blockIdx.x;
  int t = threadIdx.x;
  int n0 = dg * 512;
  int nloc = min(n - n0, 512);
  int e0 = dstart[dg], e1 = dstart[dg + 1];
  hc[t] = 0; hc[t + 256] = 0;
  __syncthreads();
  for (int j = e0 + t; j < e1; j += 256) atomicAdd(&hc[stage[j].y - n0], 1);
  __syncthreads();
  int a0 = hc[2 * t], a1 = hc[2 * t + 1];
  int s = a0 + a1;
  sc[t] = s;
  __syncthreads();
  #pragma unroll
  for (int off = 1; off < 256; off <<= 1) {
    int x = sc[t] + ((t >= off) ? sc[t - off] : 0);
    __syncthreads();
    sc[t] = x;
    __syncthreads();
  }
  int excl = sc[t] - s;
  hb[2 * t] = excl;
  hb[2 * t + 1] = excl + a0;
  cu[2 * t] = 0; cu[2 * t + 1] = 0;
  __syncthreads();
  for (int i = t; i < nloc; i += 256) {
    int node = n0 + i;
    rowptr[node] = e0 + hb[i];
    counts[node] = hc[i];
    dinv[node] = rsqrtf((float)hc[i] + 1.0f);
  }
  __syncthreads();
  for (int j = e0 + t; j < e1; j += 256) {
    int2 p = stage[j];
    int li = p.y - n0;
    int r = atomicAdd(&cu[li], 1);
    csr[e0 + hb[li] + r] = p.x;
  }
}

// ================= dense GEMM  Y[N,64](bf16) = X[N,K] @ W[K,64] =================

template <int K, bool IN_BF16>
__global__ __launch_bounds__(256) void gemm_k(const void* __restrict__ Xv,
                                              const float* __restrict__ W,
                                              u16* __restrict__ Y, int n) {
  __shared__ float XT[32][68];
  __shared__ float Ws[32][64];
  int t = threadIdx.x;
  int row0 = blockIdx.x * 64;
  int tx = t & 15, ty = t >> 4;
  float acc[4][4] = {};
  for (int kt = 0; kt < K; kt += 32) {
    {
      int r = t >> 2;
      int q = t & 3;
      int gr = row0 + r;
      #pragma unroll
      for (int h = 0; h < 2; h++) {
        int k0 = q * 8 + h * 4;
        float v0 = 0.f, v1 = 0.f, v2 = 0.f, v3 = 0.f;
        if (gr < n) {
          if (IN_BF16) {
            const ushort4 xv = *(const ushort4*)((const u16*)Xv + (size_t)gr * K + kt + k0);
            v0 = bf2f(xv.x); v1 = bf2f(xv.y); v2 = bf2f(xv.z); v3 = bf2f(xv.w);
          } else {
            const float4 xv = *(const float4*)((const float*)Xv + (size_t)gr * K + kt + k0);
            v0 = xv.x; v1 = xv.y; v2 = xv.z; v3 = xv.w;
          }
        }
        XT[k0 + 0][r] = v0;
        XT[k0 + 1][r] = v1;
        XT[k0 + 2][r] = v2;
        XT[k0 + 3][r] = v3;
      }
    }
    {
      int k = t >> 3;
      int q = t & 7;
      *(float4*)&Ws[k][q * 8 + 0] = *(const float4*)(W + (size_t)(kt + k) * 64 + q * 8);
      *(float4*)&Ws[k][q * 8 + 4] = *(const float4*)(W + (size_t)(kt + k) * 64 + q * 8 + 4);
    }
    __syncthreads();
    #pragma unroll
    for (int k = 0; k < 32; k++) {
      float4 xv = *(const float4*)&XT[k][ty * 4];
      float4 wv = *(const float4*)&Ws[k][tx * 4];
      float xa[4] = {xv.x, xv.y, xv.z, xv.w};
      float wa[4] = {wv.x, wv.y, wv.z, wv.w};
      #pragma unroll
      for (int i = 0; i < 4; i++)
        #pragma unroll
        for (int j = 0; j < 4; j++)
          acc[i][j] += xa[i] * wa[j];
    }
    __syncthreads();
  }
  #pragma unroll
  for (int i = 0; i < 4; i++) {
    int gr = row0 + ty * 4 + i;
    if (gr < n) {
      ushort4 o;
      o.x = f2bf(acc[i][0]); o.y = f2bf(acc[i][1]);
      o.z = f2bf(acc[i][2]); o.w = f2bf(acc[i][3]);
      *(ushort4*)(Y + (size_t)gr * 64 + tx * 4) = o;
    }
  }
}

// ================= edge aggregation: latency-pipelined gather =================
// 8 lanes per node, uint4 = 8 bf16 per lane. Chunks of 8 neighbors:
// coalesced csr read + shfl broadcast, 8 independent row loads in flight.

__global__ __launch_bounds__(256) void gather_k(const u16* __restrict__ xw,
                                                u16* __restrict__ hout,
                                                const int* __restrict__ rowptr,
                                                const int* __restrict__ counts,
                                                const int* __restrict__ csr,
                                                const float* __restrict__ dinv,
                                                const float* __restrict__ bias, int n) {
  int idx = blockIdx.x * 256 + threadIdx.x;
  int nid = idx >> 3;
  int lane = idx & 7;
  if (nid >= n) return;
  float di = dinv[nid];
  float sc = di * di;
  float acc[8];
  {
    uint4 a = *(const uint4*)(xw + (size_t)nid * 64 + lane * 8);
    acc[0] = bflo(a.x) * sc; acc[1] = bfhi(a.x) * sc;
    acc[2] = bflo(a.y) * sc; acc[3] = bfhi(a.y) * sc;
    acc[4] = bflo(a.z) * sc; acc[5] = bfhi(a.z) * sc;
    acc[6] = bflo(a.w) * sc; acc[7] = bfhi(a.w) * sc;
  }
  int st = rowptr[nid];
  int cn = counts[nid];
  for (int c = 0; c < cn; c += 8) {
    int rem = cn - c;  // uniform across the 8-lane group
    int myidx = 0;
    float myw = 0.f;
    if (lane < rem) {
      myidx = csr[st + c + lane];     // coalesced 32B per group
      myw = dinv[myidx] * di;
    }
    uint4 vv[8];
    float ww[8];
    #pragma unroll
    for (int i = 0; i < 8; i++) {
      if (i < rem) {
        int s = __shfl(myidx, i, 8);
        ww[i] = __shfl(myw, i, 8);
        vv[i] = *(const uint4*)(xw + (size_t)s * 64 + lane * 8);
      } else {
        ww[i] = 0.f;
        vv[i] = make_uint4(0, 0, 0, 0);
      }
    }
    #pragma unroll
    for (int i = 0; i < 8; i++) {
      float wgt = ww[i];
      acc[0] += bflo(vv[i].x) * wgt; acc[1] += bfhi(vv[i].x) * wgt;
      acc[2] += bflo(vv[i].y) * wgt; acc[3] += bfhi(vv[i].y) * wgt;
      acc[4] += bflo(vv[i].z) * wgt; acc[5] += bfhi(vv[i].z) * wgt;
      acc[6] += bflo(vv[i].w) * wgt; acc[7] += bfhi(vv[i].w) * wgt;
    }
  }
  const float4 b0 = *(const float4*)(bias + lane * 8);
  const float4 b1 = *(const float4*)(bias + lane * 8 + 4);
  acc[0] = fmaxf(acc[0] + b0.x, 0.f);
  acc[1] = fmaxf(acc[1] + b0.y, 0.f);
  acc[2] = fmaxf(acc[2] + b0.z, 0.f);
  acc[3] = fmaxf(acc[3] + b0.w, 0.f);
  acc[4] = fmaxf(acc[4] + b1.x, 0.f);
  acc[5] = fmaxf(acc[5] + b1.y, 0.f);
  acc[6] = fmaxf(acc[6] + b1.z, 0.f);
  acc[7] = fmaxf(acc[7] + b1.w, 0.f);
  uint4 o;
  o.x = ((u32)f2bf(acc[0])) | ((u32)f2bf(acc[1]) << 16);
  o.y = ((u32)f2bf(acc[2])) | ((u32)f2bf(acc[3]) << 16);
  o.z = ((u32)f2bf(acc[4])) | ((u32)f2bf(acc[5]) << 16);
  o.w = ((u32)f2bf(acc[6])) | ((u32)f2bf(acc[7]) << 16);
  *(uint4*)(hout + (size_t)nid * 64 + lane * 8) = o;
}

// ================= pooling + head =================

__global__ void bounds_k(const int* __restrict__ batch, int* __restrict__ startg, int n) {
  int t = threadIdx.x;
  if (t <= NG) {
    int lo = 0, hi = n;
    while (lo < hi) {
      int mid = (lo + hi) >> 1;
      if (batch[mid] < t) lo = mid + 1; else hi = mid;
    }
    startg[t] = lo;
  }
}

__global__ __launch_bounds__(1024) void pool_k(const u16* __restrict__ h,
                                               const int* __restrict__ startg,
                                               float* __restrict__ xcat) {
  int g = blockIdx.x;
  int s = startg[g], e = startg[g + 1];
  int lane = threadIdx.x & 63;
  int wv = threadIdx.x >> 6;
  float sum = 0.f, mx = 0.f;
  for (int nn = s + wv; nn < e; nn += 16) {
    float v = bf2f(h[(size_t)nn * 64 + lane]);
    sum += v;
    mx = fmaxf(mx, v);
  }
  __shared__ float lsum[16][64];
  __shared__ float lmax[16][64];
  lsum[wv][lane] = sum;
  lmax[wv][lane] = mx;
  __syncthreads();
  if (wv == 0) {
    #pragma unroll
    for (int i = 1; i < 16; i++) {
      sum += lsum[i][lane];
      mx = fmaxf(mx, lmax[i][lane]);
    }
    int cnt = e - s;
    xcat[g * CAT + lane]       = sum;
    xcat[g * CAT + 64 + lane]  = sum / fmaxf((float)cnt, 1.0f);
    xcat[g * CAT + 128 + lane] = mx;
  }
}

__global__ void head_k(const float* __restrict__ xcat, const float* __restrict__ Wlin,
                       const float* __restrict__ blin, float* __restrict__ out) {
  int t = threadIdx.x;
  int g = t >> 1, o = t & 1;
  float acc = blin[o];
  #pragma unroll 8
  for (int k = 0; k < CAT; k++) acc += xcat[g * CAT + k] * Wlin[k * 2 + o];
  out[g * 2 + o] = acc;
}

// ================= launch =================

extern "C" void kernel_launch(void* const* d_in, const int* in_sizes, int n_in,
                              void* d_out, int out_size, void* d_ws, size_t ws_size,
                              hipStream_t stream) {
  const float* x    = (const float*)d_in[0];
  const float* W1   = (const float*)d_in[1];
  const float* b1   = (const float*)d_in[2];
  const float* W2   = (const float*)d_in[3];
  const float* b2   = (const float*)d_in[4];
  const float* Wlin = (const float*)d_in[5];
  const float* blin = (const float*)d_in[6];
  const int*   ei   = (const int*)d_in[7];
  const int*   batch= (const int*)d_in[8];

  const int N = in_sizes[0] / IN_F;      // 100000
  const int E = in_sizes[7] / 2;         // 1600000
  const int* src = ei;
  const int* dst = ei + E;
  const int ndig = (N + 511) >> 9;       // 196
  const int nbE  = (E + 4095) / 4096;    // 391

  char* w = (char*)d_ws;
  auto alloc = [&](size_t bytes) {
    void* p = (void*)w;
    w += (bytes + 255) & ~(size_t)255;
    return p;
  };
  int*   rowptr = (int*)alloc((size_t)N * 4);
  int*   counts = (int*)alloc((size_t)N * 4);
  float* dinv   = (float*)alloc((size_t)N * 4);
  int*   csr    = (int*)alloc((size_t)E * 4);
  int*   ghist  = (int*)alloc(256 * 4);
  int*   dstart = (int*)alloc(260 * 4);
  int*   gcur   = (int*)alloc(256 * 4);
  int*   startg = (int*)alloc((NG + 2) * 4);
  u16*   bufA   = (u16*)alloc((size_t)N * 64 * 2);
  u16*   bufB   = (u16*)alloc((size_t)N * 64 * 2);
  int2*  stage  = (int2*)alloc((size_t)E * 8);

  float* xcat = (float*)d_out;
  float* outh = (float*)d_out + NG * CAT;

  hipMemsetAsync(ghist, 0, 256 * 4, stream);
  hist_k  <<<nbE, 256, 0, stream>>>(dst, E, ghist, ndig);
  dscan_k <<<1, 256, 0, stream>>>(ghist, dstart, gcur, ndig, E);
  stage_k <<<nbE, 256, 0, stream>>>(src, dst, E, gcur, stage, ndig);
  csr_k   <<<ndig, 256, 0, stream>>>(stage, dstart, rowptr, counts, dinv, csr, N);

  // layer 1
  gemm_k<IN_F, false> <<<(N + 63) / 64, 256, 0, stream>>>(x, W1, bufA, N);
  gather_k <<<(N * 8 + 255) / 256, 256, 0, stream>>>(bufA, bufB, rowptr, counts, csr, dinv, b1, N);

  // layer 2
  gemm_k<C1, true> <<<(N + 63) / 64, 256, 0, stream>>>(bufB, W2, bufA, N);
  gather_k <<<(N * 8 + 255) / 256, 256, 0, stream>>>(bufA, bufB, rowptr, counts, csr, dinv, b2, N);

  // pooling + head
  bounds_k <<<1, 256, 0, stream>>>(batch, startg, N);
  pool_k <<<NG, 1024, 0, stream>>>(bufB, startg, xcat);
  head_k <<<1, 256, 0, stream>>>(xcat, Wlin, blin, outh);
}

// Round 5
// 205.915 us; speedup vs baseline: 1.4671x; 1.0384x over previous
//
#include <hip/hip_runtime.h>

#define IN_F 128
#define C1 64
#define NG 128
#define CAT 192

typedef unsigned short u16;
typedef unsigned int u32;

__device__ inline u16 f2bf(float f) {
  u32 u = __float_as_uint(f);
  u = (u + 0x7FFFu + ((u >> 16) & 1u)) >> 16;   // RTNE
  return (u16)u;
}
__device__ inline float bf2f(u16 h) { return __uint_as_float(((u32)h) << 16); }
__device__ inline float bflo(u32 p) { return __uint_as_float(p << 16); }
__device__ inline float bfhi(u32 p) { return __uint_as_float(p & 0xFFFF0000u); }

// ================= CSR build (locality-clean) =================
// digit = dst >> 9  (512 nodes per digit)

__global__ void zeroh_k(int* __restrict__ g) { g[threadIdx.x] = 0; }

__global__ __launch_bounds__(256) void hist_k(const int* __restrict__ dst, int e,
                                              int* __restrict__ ghist, int ndig) {
  __shared__ int h[256];
  int t = threadIdx.x;
  h[t] = 0;
  __syncthreads();
  int base = blockIdx.x * 4096;
  #pragma unroll
  for (int i = 0; i < 16; i++) {
    int j = base + t + i * 256;
    if (j < e) atomicAdd(&h[dst[j] >> 9], 1);
  }
  __syncthreads();
  if (t < ndig && h[t] > 0) atomicAdd(&ghist[t], h[t]);
}

__global__ void dscan_k(const int* __restrict__ ghist, int* __restrict__ dstart,
                        int* __restrict__ gcur, int ndig, int e) {
  __shared__ int lds[256];
  int t = threadIdx.x;
  int v = (t < ndig) ? ghist[t] : 0;
  lds[t] = v;
  __syncthreads();
  #pragma unroll
  for (int off = 1; off < 256; off <<= 1) {
    int x = lds[t] + ((t >= off) ? lds[t - off] : 0);
    __syncthreads();
    lds[t] = x;
    __syncthreads();
  }
  int excl = lds[t] - v;
  if (t < ndig) { dstart[t] = excl; gcur[t] = excl; }
  if (t == 0) dstart[ndig] = e;
}

__global__ __launch_bounds__(256) void stage_k(const int* __restrict__ src,
                                               const int* __restrict__ dst, int e,
                                               int* __restrict__ gcur,
                                               int2* __restrict__ stage, int ndig) {
  __shared__ int h[256];
  __shared__ int cur[256];
  int t = threadIdx.x;
  h[t] = 0;
  __syncthreads();
  int base = blockIdx.x * 4096;
  int mys[16], myd[16];
  #pragma unroll
  for (int i = 0; i < 16; i++) {
    int j = base + t + i * 256;
    if (j < e) {
      mys[i] = src[j];
      myd[i] = dst[j];
      atomicAdd(&h[myd[i] >> 9], 1);
    } else {
      myd[i] = -1;
    }
  }
  __syncthreads();
  int cnt = h[t];
  __syncthreads();
  int gbase = 0;
  if (t < ndig && cnt > 0) gbase = atomicAdd(&gcur[t], cnt);
  h[t] = gbase;
  cur[t] = 0;
  __syncthreads();
  #pragma unroll
  for (int i = 0; i < 16; i++) {
    if (myd[i] >= 0) {
      int d = myd[i] >> 9;
      int r = atomicAdd(&cur[d], 1);
      stage[h[d] + r] = make_int2(mys[i], myd[i]);
    }
  }
}

__global__ __launch_bounds__(256) void csr_k(const int2* __restrict__ stage,
                                             const int* __restrict__ dstart,
                                             int* __restrict__ rowptr,
                                             int* __restrict__ counts,
                                             float* __restrict__ dinv,
                                             int* __restrict__ csr, int n) {
  __shared__ int hc[512];
  __shared__ int hb[512];
  __shared__ int cu[512];
  __shared__ int sc[256];
  int dg = blockIdx.x;
  int t = threadIdx.x;
  int n0 = dg * 512;
  int nloc = min(n - n0, 512);
  int e0 = dstart[dg], e1 = dstart[dg + 1];
  hc[t] = 0; hc[t + 256] = 0;
  __syncthreads();
  for (int j = e0 + t; j < e1; j += 256) atomicAdd(&hc[stage[j].y - n0], 1);
  __syncthreads();
  int a0 = hc[2 * t], a1 = hc[2 * t + 1];
  int s = a0 + a1;
  sc[t] = s;
  __syncthreads();
  #pragma unroll
  for (int off = 1; off < 256; off <<= 1) {
    int x = sc[t] + ((t >= off) ? sc[t - off] : 0);
    __syncthreads();
    sc[t] = x;
    __syncthreads();
  }
  int excl = sc[t] - s;
  hb[2 * t] = excl;
  hb[2 * t + 1] = excl + a0;
  cu[2 * t] = 0; cu[2 * t + 1] = 0;
  __syncthreads();
  for (int i = t; i < nloc; i += 256) {
    int node = n0 + i;
    rowptr[node] = e0 + hb[i];
    counts[node] = hc[i];
    dinv[node] = rsqrtf((float)hc[i] + 1.0f);
  }
  __syncthreads();
  for (int j = e0 + t; j < e1; j += 256) {
    int2 p = stage[j];
    int li = p.y - n0;
    int r = atomicAdd(&cu[li], 1);
    csr[e0 + hb[li] + r] = p.x;
  }
}

// ================= dense GEMM  Y[N,64](bf16) = X[N,K] @ W[K,64] =================

template <int K, bool IN_BF16>
__global__ __launch_bounds__(256) void gemm_k(const void* __restrict__ Xv,
                                              const float* __restrict__ W,
                                              u16* __restrict__ Y, int n) {
  __shared__ float XT[32][68];
  __shared__ float Ws[32][64];
  int t = threadIdx.x;
  int row0 = blockIdx.x * 64;
  int tx = t & 15, ty = t >> 4;
  float acc[4][4] = {};
  for (int kt = 0; kt < K; kt += 32) {
    {
      int r = t >> 2;
      int q = t & 3;
      int gr = row0 + r;
      #pragma unroll
      for (int h = 0; h < 2; h++) {
        int k0 = q * 8 + h * 4;
        float v0 = 0.f, v1 = 0.f, v2 = 0.f, v3 = 0.f;
        if (gr < n) {
          if (IN_BF16) {
            const ushort4 xv = *(const ushort4*)((const u16*)Xv + (size_t)gr * K + kt + k0);
            v0 = bf2f(xv.x); v1 = bf2f(xv.y); v2 = bf2f(xv.z); v3 = bf2f(xv.w);
          } else {
            const float4 xv = *(const float4*)((const float*)Xv + (size_t)gr * K + kt + k0);
            v0 = xv.x; v1 = xv.y; v2 = xv.z; v3 = xv.w;
          }
        }
        XT[k0 + 0][r] = v0;
        XT[k0 + 1][r] = v1;
        XT[k0 + 2][r] = v2;
        XT[k0 + 3][r] = v3;
      }
    }
    {
      int k = t >> 3;
      int q = t & 7;
      *(float4*)&Ws[k][q * 8 + 0] = *(const float4*)(W + (size_t)(kt + k) * 64 + q * 8);
      *(float4*)&Ws[k][q * 8 + 4] = *(const float4*)(W + (size_t)(kt + k) * 64 + q * 8 + 4);
    }
    __syncthreads();
    #pragma unroll
    for (int k = 0; k < 32; k++) {
      float4 xv = *(const float4*)&XT[k][ty * 4];
      float4 wv = *(const float4*)&Ws[k][tx * 4];
      float xa[4] = {xv.x, xv.y, xv.z, xv.w};
      float wa[4] = {wv.x, wv.y, wv.z, wv.w};
      #pragma unroll
      for (int i = 0; i < 4; i++)
        #pragma unroll
        for (int j = 0; j < 4; j++)
          acc[i][j] += xa[i] * wa[j];
    }
    __syncthreads();
  }
  #pragma unroll
  for (int i = 0; i < 4; i++) {
    int gr = row0 + ty * 4 + i;
    if (gr < n) {
      ushort4 o;
      o.x = f2bf(acc[i][0]); o.y = f2bf(acc[i][1]);
      o.z = f2bf(acc[i][2]); o.w = f2bf(acc[i][3]);
      *(ushort4*)(Y + (size_t)gr * 64 + tx * 4) = o;
    }
  }
}

// ================= edge aggregation: latency-pipelined gather =================

__global__ __launch_bounds__(256) void gather_k(const u16* __restrict__ xw,
                                                u16* __restrict__ hout,
                                                const int* __restrict__ rowptr,
                                                const int* __restrict__ counts,
                                                const int* __restrict__ csr,
                                                const float* __restrict__ dinv,
                                                const float* __restrict__ bias, int n) {
  int idx = blockIdx.x * 256 + threadIdx.x;
  int nid = idx >> 3;
  int lane = idx & 7;
  if (nid >= n) return;
  float di = dinv[nid];
  float sc = di * di;
  float acc[8];
  {
    uint4 a = *(const uint4*)(xw + (size_t)nid * 64 + lane * 8);
    acc[0] = bflo(a.x) * sc; acc[1] = bfhi(a.x) * sc;
    acc[2] = bflo(a.y) * sc; acc[3] = bfhi(a.y) * sc;
    acc[4] = bflo(a.z) * sc; acc[5] = bfhi(a.z) * sc;
    acc[6] = bflo(a.w) * sc; acc[7] = bfhi(a.w) * sc;
  }
  int st = rowptr[nid];
  int cn = counts[nid];
  for (int c = 0; c < cn; c += 8) {
    int rem = cn - c;  // uniform across the 8-lane group
    int myidx = 0;
    float myw = 0.f;
    if (lane < rem) {
      myidx = csr[st + c + lane];
      myw = dinv[myidx] * di;
    }
    uint4 vv[8];
    float ww[8];
    #pragma unroll
    for (int i = 0; i < 8; i++) {
      if (i < rem) {
        int s = __shfl(myidx, i, 8);
        ww[i] = __shfl(myw, i, 8);
        vv[i] = *(const uint4*)(xw + (size_t)s * 64 + lane * 8);
      } else {
        ww[i] = 0.f;
        vv[i] = make_uint4(0, 0, 0, 0);
      }
    }
    #pragma unroll
    for (int i = 0; i < 8; i++) {
      float wgt = ww[i];
      acc[0] += bflo(vv[i].x) * wgt; acc[1] += bfhi(vv[i].x) * wgt;
      acc[2] += bflo(vv[i].y) * wgt; acc[3] += bfhi(vv[i].y) * wgt;
      acc[4] += bflo(vv[i].z) * wgt; acc[5] += bfhi(vv[i].z) * wgt;
      acc[6] += bflo(vv[i].w) * wgt; acc[7] += bfhi(vv[i].w) * wgt;
    }
  }
  const float4 b0 = *(const float4*)(bias + lane * 8);
  const float4 b1 = *(const float4*)(bias + lane * 8 + 4);
  acc[0] = fmaxf(acc[0] + b0.x, 0.f);
  acc[1] = fmaxf(acc[1] + b0.y, 0.f);
  acc[2] = fmaxf(acc[2] + b0.z, 0.f);
  acc[3] = fmaxf(acc[3] + b0.w, 0.f);
  acc[4] = fmaxf(acc[4] + b1.x, 0.f);
  acc[5] = fmaxf(acc[5] + b1.y, 0.f);
  acc[6] = fmaxf(acc[6] + b1.z, 0.f);
  acc[7] = fmaxf(acc[7] + b1.w, 0.f);
  uint4 o;
  o.x = ((u32)f2bf(acc[0])) | ((u32)f2bf(acc[1]) << 16);
  o.y = ((u32)f2bf(acc[2])) | ((u32)f2bf(acc[3]) << 16);
  o.z = ((u32)f2bf(acc[4])) | ((u32)f2bf(acc[5]) << 16);
  o.w = ((u32)f2bf(acc[6])) | ((u32)f2bf(acc[7]) << 16);
  *(uint4*)(hout + (size_t)nid * 64 + lane * 8) = o;
}

// ================= fused pooling + head =================
// One block per graph: binary-search bounds, strided sum/max, LDS reduce,
// then the first wave computes xcat writes AND the 2-wide head dot product.

__global__ __launch_bounds__(1024) void pool_k(const u16* __restrict__ h,
                                               const int* __restrict__ batch, int n,
                                               const float* __restrict__ Wlin,
                                               const float* __restrict__ blin,
                                               float* __restrict__ xcat,
                                               float* __restrict__ outh) {
  int g = blockIdx.x;
  __shared__ int se[2];
  if (threadIdx.x < 2) {
    int target = g + (int)threadIdx.x;
    int lo = 0, hi = n;
    while (lo < hi) {
      int mid = (lo + hi) >> 1;
      if (batch[mid] < target) lo = mid + 1; else hi = mid;
    }
    se[threadIdx.x] = lo;
  }
  __syncthreads();
  int s = se[0], e = se[1];
  int lane = threadIdx.x & 63;
  int wv = threadIdx.x >> 6;
  float sum = 0.f, mx = 0.f;  // relu output >= 0 -> 0-init max matches ref
  for (int nn = s + wv; nn < e; nn += 16) {
    float v = bf2f(h[(size_t)nn * 64 + lane]);
    sum += v;
    mx = fmaxf(mx, v);
  }
  __shared__ float lsum[16][64];
  __shared__ float lmax[16][64];
  lsum[wv][lane] = sum;
  lmax[wv][lane] = mx;
  __syncthreads();
  if (wv == 0) {
    #pragma unroll
    for (int i = 1; i < 16; i++) {
      sum += lsum[i][lane];
      mx = fmaxf(mx, lmax[i][lane]);
    }
    int cnt = e - s;
    float x0 = sum;
    float x1 = sum / fmaxf((float)cnt, 1.0f);
    float x2 = mx;
    xcat[g * CAT + lane]       = x0;
    xcat[g * CAT + 64 + lane]  = x1;
    xcat[g * CAT + 128 + lane] = x2;
    #pragma unroll
    for (int o = 0; o < 2; o++) {
      float p = x0 * Wlin[lane * 2 + o] +
                x1 * Wlin[(64 + lane) * 2 + o] +
                x2 * Wlin[(128 + lane) * 2 + o];
      #pragma unroll
      for (int off = 32; off > 0; off >>= 1) p += __shfl_down(p, off, 64);
      if (lane == 0) outh[g * 2 + o] = p + blin[o];
    }
  }
}

// ================= launch =================

extern "C" void kernel_launch(void* const* d_in, const int* in_sizes, int n_in,
                              void* d_out, int out_size, void* d_ws, size_t ws_size,
                              hipStream_t stream) {
  const float* x    = (const float*)d_in[0];
  const float* W1   = (const float*)d_in[1];
  const float* b1   = (const float*)d_in[2];
  const float* W2   = (const float*)d_in[3];
  const float* b2   = (const float*)d_in[4];
  const float* Wlin = (const float*)d_in[5];
  const float* blin = (const float*)d_in[6];
  const int*   ei   = (const int*)d_in[7];
  const int*   batch= (const int*)d_in[8];

  const int N = in_sizes[0] / IN_F;      // 100000
  const int E = in_sizes[7] / 2;         // 1600000
  const int* src = ei;
  const int* dst = ei + E;
  const int ndig = (N + 511) >> 9;       // 196
  const int nbE  = (E + 4095) / 4096;    // 391

  char* w = (char*)d_ws;
  auto alloc = [&](size_t bytes) {
    void* p = (void*)w;
    w += (bytes + 255) & ~(size_t)255;
    return p;
  };
  int*   rowptr = (int*)alloc((size_t)N * 4);
  int*   counts = (int*)alloc((size_t)N * 4);
  float* dinv   = (float*)alloc((size_t)N * 4);
  int*   csr    = (int*)alloc((size_t)E * 4);
  int*   ghist  = (int*)alloc(256 * 4);
  int*   dstart = (int*)alloc(260 * 4);
  int*   gcur   = (int*)alloc(256 * 4);
  u16*   bufA   = (u16*)alloc((size_t)N * 64 * 2);
  u16*   bufB   = (u16*)alloc((size_t)N * 64 * 2);
  int2*  stage  = (int2*)alloc((size_t)E * 8);

  float* xcat = (float*)d_out;
  float* outh = (float*)d_out + NG * CAT;

  zeroh_k <<<1, 256, 0, stream>>>(ghist);
  hist_k  <<<nbE, 256, 0, stream>>>(dst, E, ghist, ndig);
  dscan_k <<<1, 256, 0, stream>>>(ghist, dstart, gcur, ndig, E);
  stage_k <<<nbE, 256, 0, stream>>>(src, dst, E, gcur, stage, ndig);
  csr_k   <<<ndig, 256, 0, stream>>>(stage, dstart, rowptr, counts, dinv, csr, N);

  // layer 1
  gemm_k<IN_F, false> <<<(N + 63) / 64, 256, 0, stream>>>(x, W1, bufA, N);
  gather_k <<<(N * 8 + 255) / 256, 256, 0, stream>>>(bufA, bufB, rowptr, counts, csr, dinv, b1, N);

  // layer 2
  gemm_k<C1, true> <<<(N + 63) / 64, 256, 0, stream>>>(bufB, W2, bufA, N);
  gather_k <<<(N * 8 + 255) / 256, 256, 0, stream>>>(bufA, bufB, rowptr, counts, csr, dinv, b2, N);

  // fused pooling + head
  pool_k <<<NG, 1024, 0, stream>>>(bufB, batch, N, Wlin, blin, xcat, outh);
}

// Round 6
// 185.559 us; speedup vs baseline: 1.6281x; 1.1097x over previous
//
#include <hip/hip_runtime.h>

#define IN_F 128
#define C1 64
#define NG 128
#define CAT 192
#define DCAP 10240   // per-digit edge capacity (mean 8163, sigma ~90)

typedef unsigned short u16;
typedef unsigned int u32;

__device__ inline u16 f2bf(float f) {
  u32 u = __float_as_uint(f);
  u = (u + 0x7FFFu + ((u >> 16) & 1u)) >> 16;   // RTNE
  return (u16)u;
}
__device__ inline float bf2f(u16 h) { return __uint_as_float(((u32)h) << 16); }
__device__ inline float bflo(u32 p) { return __uint_as_float(p << 16); }
__device__ inline float bfhi(u32 p) { return __uint_as_float(p & 0xFFFF0000u); }

// ================= CSR build (bucketed, no global scan) =================
// digit = dst >> 9 (512 nodes per digit); per-digit bucket of DCAP slots.

__global__ void zeroh_k(int* __restrict__ g) { g[threadIdx.x] = 0; }

__global__ __launch_bounds__(256) void stage_k(const int* __restrict__ src,
                                               const int* __restrict__ dst, int e,
                                               int* __restrict__ gcur,
                                               int2* __restrict__ stage, int ndig) {
  __shared__ int h[256];    // local digit counts -> global claimed base
  __shared__ int cur[256];  // local rank cursors
  int t = threadIdx.x;
  h[t] = 0;
  __syncthreads();
  int base = blockIdx.x * 4096;
  int mys[16], myd[16];
  #pragma unroll
  for (int i = 0; i < 16; i++) {
    int j = base + t + i * 256;
    if (j < e) {
      mys[i] = src[j];
      myd[i] = dst[j];
      atomicAdd(&h[myd[i] >> 9], 1);
    } else {
      myd[i] = -1;
    }
  }
  __syncthreads();
  int cnt = h[t];
  __syncthreads();
  int gbase = 0;
  if (t < ndig && cnt > 0) gbase = atomicAdd(&gcur[t], cnt);
  h[t] = gbase;
  cur[t] = 0;
  __syncthreads();
  #pragma unroll
  for (int i = 0; i < 16; i++) {
    if (myd[i] >= 0) {
      int d = myd[i] >> 9;
      int r = atomicAdd(&cur[d], 1);
      stage[(size_t)d * DCAP + h[d] + r] = make_int2(mys[i], myd[i]);
    }
  }
}

// one block per digit: rowptr/counts/dinv + scatter src into the digit's csr bucket.
__global__ __launch_bounds__(256) void csr_k(const int2* __restrict__ stage,
                                             const int* __restrict__ gcur,
                                             int* __restrict__ rowptr,
                                             int* __restrict__ counts,
                                             float* __restrict__ dinv,
                                             int* __restrict__ csr, int n) {
  __shared__ int hc[512];
  __shared__ int hb[512];
  __shared__ int cu[512];
  __shared__ int sc[256];
  int dg = blockIdx.x;
  int t = threadIdx.x;
  int n0 = dg * 512;
  int nloc = min(n - n0, 512);
  int e0 = dg * DCAP;
  int e1 = e0 + gcur[dg];
  hc[t] = 0; hc[t + 256] = 0;
  __syncthreads();
  for (int j = e0 + t; j < e1; j += 256) atomicAdd(&hc[stage[j].y - n0], 1);
  __syncthreads();
  int a0 = hc[2 * t], a1 = hc[2 * t + 1];
  int s = a0 + a1;
  sc[t] = s;
  __syncthreads();
  #pragma unroll
  for (int off = 1; off < 256; off <<= 1) {
    int x = sc[t] + ((t >= off) ? sc[t - off] : 0);
    __syncthreads();
    sc[t] = x;
    __syncthreads();
  }
  int excl = sc[t] - s;
  hb[2 * t] = excl;
  hb[2 * t + 1] = excl + a0;
  cu[2 * t] = 0; cu[2 * t + 1] = 0;
  __syncthreads();
  for (int i = t; i < nloc; i += 256) {
    int node = n0 + i;
    rowptr[node] = e0 + hb[i];
    counts[node] = hc[i];
    dinv[node] = rsqrtf((float)hc[i] + 1.0f);  // +1 self loop
  }
  __syncthreads();
  for (int j = e0 + t; j < e1; j += 256) {
    int2 p = stage[j];
    int li = p.y - n0;
    int r = atomicAdd(&cu[li], 1);
    csr[e0 + hb[li] + r] = p.x;
  }
}

// ================= dense GEMM  Y[N,64](bf16) = X[N,K] @ W[K,64] =================

template <int K, bool IN_BF16>
__global__ __launch_bounds__(256) void gemm_k(const void* __restrict__ Xv,
                                              const float* __restrict__ W,
                                              u16* __restrict__ Y, int n) {
  __shared__ float XT[32][68];
  __shared__ float Ws[32][64];
  int t = threadIdx.x;
  int row0 = blockIdx.x * 64;
  int tx = t & 15, ty = t >> 4;
  float acc[4][4] = {};
  for (int kt = 0; kt < K; kt += 32) {
    {
      int r = t >> 2;
      int q = t & 3;
      int gr = row0 + r;
      #pragma unroll
      for (int h = 0; h < 2; h++) {
        int k0 = q * 8 + h * 4;
        float v0 = 0.f, v1 = 0.f, v2 = 0.f, v3 = 0.f;
        if (gr < n) {
          if (IN_BF16) {
            const ushort4 xv = *(const ushort4*)((const u16*)Xv + (size_t)gr * K + kt + k0);
            v0 = bf2f(xv.x); v1 = bf2f(xv.y); v2 = bf2f(xv.z); v3 = bf2f(xv.w);
          } else {
            const float4 xv = *(const float4*)((const float*)Xv + (size_t)gr * K + kt + k0);
            v0 = xv.x; v1 = xv.y; v2 = xv.z; v3 = xv.w;
          }
        }
        XT[k0 + 0][r] = v0;
        XT[k0 + 1][r] = v1;
        XT[k0 + 2][r] = v2;
        XT[k0 + 3][r] = v3;
      }
    }
    {
      int k = t >> 3;
      int q = t & 7;
      *(float4*)&Ws[k][q * 8 + 0] = *(const float4*)(W + (size_t)(kt + k) * 64 + q * 8);
      *(float4*)&Ws[k][q * 8 + 4] = *(const float4*)(W + (size_t)(kt + k) * 64 + q * 8 + 4);
    }
    __syncthreads();
    #pragma unroll
    for (int k = 0; k < 32; k++) {
      float4 xv = *(const float4*)&XT[k][ty * 4];
      float4 wv = *(const float4*)&Ws[k][tx * 4];
      float xa[4] = {xv.x, xv.y, xv.z, xv.w};
      float wa[4] = {wv.x, wv.y, wv.z, wv.w};
      #pragma unroll
      for (int i = 0; i < 4; i++)
        #pragma unroll
        for (int j = 0; j < 4; j++)
          acc[i][j] += xa[i] * wa[j];
    }
    __syncthreads();
  }
  #pragma unroll
  for (int i = 0; i < 4; i++) {
    int gr = row0 + ty * 4 + i;
    if (gr < n) {
      ushort4 o;
      o.x = f2bf(acc[i][0]); o.y = f2bf(acc[i][1]);
      o.z = f2bf(acc[i][2]); o.w = f2bf(acc[i][3]);
      *(ushort4*)(Y + (size_t)gr * 64 + tx * 4) = o;
    }
  }
}

// ================= edge aggregation: pipelined gather =================
// 8 lanes/node, 8 bf16 per lane. Per chunk: csr+dinv loads issue together,
// row loads issue right after index shfl, next chunk's csr+dinv prefetched
// before the FMA pass.

__global__ __launch_bounds__(256) void gather_k(const u16* __restrict__ xw,
                                                u16* __restrict__ hout,
                                                const int* __restrict__ rowptr,
                                                const int* __restrict__ counts,
                                                const int* __restrict__ csr,
                                                const float* __restrict__ dinv,
                                                const float* __restrict__ bias, int n) {
  int idx = blockIdx.x * 256 + threadIdx.x;
  int nid = idx >> 3;
  int lane = idx & 7;
  if (nid >= n) return;
  float di = dinv[nid];
  float sc = di * di;
  float acc[8];
  {
    uint4 a = *(const uint4*)(xw + (size_t)nid * 64 + lane * 8);
    acc[0] = bflo(a.x) * sc; acc[1] = bfhi(a.x) * sc;
    acc[2] = bflo(a.y) * sc; acc[3] = bfhi(a.y) * sc;
    acc[4] = bflo(a.z) * sc; acc[5] = bfhi(a.z) * sc;
    acc[6] = bflo(a.w) * sc; acc[7] = bfhi(a.w) * sc;
  }
  int st = rowptr[nid];
  int cn = counts[nid];
  // prologue loads for chunk 0
  int myidx = 0;
  float dv = 0.f;
  if (lane < cn) {
    myidx = csr[st + lane];
    dv = dinv[myidx];
  }
  for (int c = 0; c < cn; c += 8) {
    int rem = cn - c;
    // broadcast indices, issue row loads immediately
    uint4 vv[8];
    #pragma unroll
    for (int i = 0; i < 8; i++) {
      int s = __shfl(myidx, i, 8);
      if (i < rem) {
        vv[i] = *(const uint4*)(xw + (size_t)s * 64 + lane * 8);
      } else {
        vv[i] = make_uint4(0, 0, 0, 0);
      }
    }
    // weight broadcast (dinv load issued in prologue / previous prefetch)
    float ww[8];
    float myw = dv * di;
    #pragma unroll
    for (int i = 0; i < 8; i++) ww[i] = (i < rem) ? __shfl(myw, i, 8) : 0.f;
    // prefetch next chunk's csr + dinv while rows are in flight
    int nxt = 0;
    float ndv = 0.f;
    if (c + 8 < cn && lane < rem - 8) {
      nxt = csr[st + c + 8 + lane];
      ndv = dinv[nxt];
    }
    #pragma unroll
    for (int i = 0; i < 8; i++) {
      float wgt = ww[i];
      acc[0] += bflo(vv[i].x) * wgt; acc[1] += bfhi(vv[i].x) * wgt;
      acc[2] += bflo(vv[i].y) * wgt; acc[3] += bfhi(vv[i].y) * wgt;
      acc[4] += bflo(vv[i].z) * wgt; acc[5] += bfhi(vv[i].z) * wgt;
      acc[6] += bflo(vv[i].w) * wgt; acc[7] += bfhi(vv[i].w) * wgt;
    }
    myidx = nxt;
    dv = ndv;
  }
  const float4 b0 = *(const float4*)(bias + lane * 8);
  const float4 b1 = *(const float4*)(bias + lane * 8 + 4);
  acc[0] = fmaxf(acc[0] + b0.x, 0.f);
  acc[1] = fmaxf(acc[1] + b0.y, 0.f);
  acc[2] = fmaxf(acc[2] + b0.z, 0.f);
  acc[3] = fmaxf(acc[3] + b0.w, 0.f);
  acc[4] = fmaxf(acc[4] + b1.x, 0.f);
  acc[5] = fmaxf(acc[5] + b1.y, 0.f);
  acc[6] = fmaxf(acc[6] + b1.z, 0.f);
  acc[7] = fmaxf(acc[7] + b1.w, 0.f);
  uint4 o;
  o.x = ((u32)f2bf(acc[0])) | ((u32)f2bf(acc[1]) << 16);
  o.y = ((u32)f2bf(acc[2])) | ((u32)f2bf(acc[3]) << 16);
  o.z = ((u32)f2bf(acc[4])) | ((u32)f2bf(acc[5]) << 16);
  o.w = ((u32)f2bf(acc[6])) | ((u32)f2bf(acc[7]) << 16);
  *(uint4*)(hout + (size_t)nid * 64 + lane * 8) = o;
}

// ================= fused pooling + head =================

__global__ __launch_bounds__(1024) void pool_k(const u16* __restrict__ h,
                                               const int* __restrict__ batch, int n,
                                               const float* __restrict__ Wlin,
                                               const float* __restrict__ blin,
                                               float* __restrict__ xcat,
                                               float* __restrict__ outh) {
  int g = blockIdx.x;
  __shared__ int se[2];
  if (threadIdx.x < 2) {
    int target = g + (int)threadIdx.x;
    int lo = 0, hi = n;
    while (lo < hi) {
      int mid = (lo + hi) >> 1;
      if (batch[mid] < target) lo = mid + 1; else hi = mid;
    }
    se[threadIdx.x] = lo;
  }
  __syncthreads();
  int s = se[0], e = se[1];
  int lane = threadIdx.x & 63;
  int wv = threadIdx.x >> 6;
  float sum = 0.f, mx = 0.f;  // relu >= 0 -> 0-init max matches ref
  for (int nn = s + wv; nn < e; nn += 16) {
    float v = bf2f(h[(size_t)nn * 64 + lane]);
    sum += v;
    mx = fmaxf(mx, v);
  }
  __shared__ float lsum[16][64];
  __shared__ float lmax[16][64];
  lsum[wv][lane] = sum;
  lmax[wv][lane] = mx;
  __syncthreads();
  if (wv == 0) {
    #pragma unroll
    for (int i = 1; i < 16; i++) {
      sum += lsum[i][lane];
      mx = fmaxf(mx, lmax[i][lane]);
    }
    int cnt = e - s;
    float x0 = sum;
    float x1 = sum / fmaxf((float)cnt, 1.0f);
    float x2 = mx;
    xcat[g * CAT + lane]       = x0;
    xcat[g * CAT + 64 + lane]  = x1;
    xcat[g * CAT + 128 + lane] = x2;
    #pragma unroll
    for (int o = 0; o < 2; o++) {
      float p = x0 * Wlin[lane * 2 + o] +
                x1 * Wlin[(64 + lane) * 2 + o] +
                x2 * Wlin[(128 + lane) * 2 + o];
      #pragma unroll
      for (int off = 32; off > 0; off >>= 1) p += __shfl_down(p, off, 64);
      if (lane == 0) outh[g * 2 + o] = p + blin[o];
    }
  }
}

// ================= launch =================

extern "C" void kernel_launch(void* const* d_in, const int* in_sizes, int n_in,
                              void* d_out, int out_size, void* d_ws, size_t ws_size,
                              hipStream_t stream) {
  const float* x    = (const float*)d_in[0];
  const float* W1   = (const float*)d_in[1];
  const float* b1   = (const float*)d_in[2];
  const float* W2   = (const float*)d_in[3];
  const float* b2   = (const float*)d_in[4];
  const float* Wlin = (const float*)d_in[5];
  const float* blin = (const float*)d_in[6];
  const int*   ei   = (const int*)d_in[7];
  const int*   batch= (const int*)d_in[8];

  const int N = in_sizes[0] / IN_F;      // 100000
  const int E = in_sizes[7] / 2;         // 1600000
  const int* src = ei;
  const int* dst = ei + E;
  const int ndig = (N + 511) >> 9;       // 196
  const int nbE  = (E + 4095) / 4096;    // 391

  char* w = (char*)d_ws;
  auto alloc = [&](size_t bytes) {
    void* p = (void*)w;
    w += (bytes + 255) & ~(size_t)255;
    return p;
  };
  int*   rowptr = (int*)alloc((size_t)N * 4);
  int*   counts = (int*)alloc((size_t)N * 4);
  float* dinv   = (float*)alloc((size_t)N * 4);
  int*   csr    = (int*)alloc((size_t)ndig * DCAP * 4);
  int*   gcur   = (int*)alloc(256 * 4);
  u16*   bufA   = (u16*)alloc((size_t)N * 64 * 2);
  u16*   bufB   = (u16*)alloc((size_t)N * 64 * 2);
  int2*  stage  = (int2*)alloc((size_t)ndig * DCAP * 8);

  float* xcat = (float*)d_out;
  float* outh = (float*)d_out + NG * CAT;

  zeroh_k <<<1, 256, 0, stream>>>(gcur);
  stage_k <<<nbE, 256, 0, stream>>>(src, dst, E, gcur, stage, ndig);
  csr_k   <<<ndig, 256, 0, stream>>>(stage, gcur, rowptr, counts, dinv, csr, N);

  // layer 1
  gemm_k<IN_F, false> <<<(N + 63) / 64, 256, 0, stream>>>(x, W1, bufA, N);
  gather_k <<<(N * 8 + 255) / 256, 256, 0, stream>>>(bufA, bufB, rowptr, counts, csr, dinv, b1, N);

  // layer 2
  gemm_k<C1, true> <<<(N + 63) / 64, 256, 0, stream>>>(bufB, W2, bufA, N);
  gather_k <<<(N * 8 + 255) / 256, 256, 0, stream>>>(bufA, bufB, rowptr, counts, csr, dinv, b2, N);

  // fused pooling + head
  pool_k <<<NG, 1024, 0, stream>>>(bufB, batch, N, Wlin, blin, xcat, outh);
}

// Round 7
// 166.729 us; speedup vs baseline: 1.8119x; 1.1129x over previous
//
#include <hip/hip_runtime.h>

#define IN_F 128
#define C1 64
#define NG 128
#define CAT 192
#define DCAP 10240   // per-digit edge capacity (mean 8163, sigma ~90)

typedef unsigned short u16;
typedef unsigned int u32;
typedef __attribute__((ext_vector_type(8))) short bf16x8;
typedef __attribute__((ext_vector_type(4))) float f32x4;

__device__ inline u16 f2bf(float f) {
  u32 u = __float_as_uint(f);
  u = (u + 0x7FFFu + ((u >> 16) & 1u)) >> 16;   // RTNE
  return (u16)u;
}
__device__ inline float bf2f(u16 h) { return __uint_as_float(((u32)h) << 16); }
__device__ inline float bflo(u32 p) { return __uint_as_float(p << 16); }
__device__ inline float bfhi(u32 p) { return __uint_as_float(p & 0xFFFF0000u); }

// ================= CSR build (bucketed, no global scan) =================

__global__ void zeroh_k(int* __restrict__ g) { g[threadIdx.x] = 0; }

__global__ __launch_bounds__(256) void stage_k(const int* __restrict__ src,
                                               const int* __restrict__ dst, int e,
                                               int* __restrict__ gcur,
                                               int2* __restrict__ stage, int ndig) {
  __shared__ int h[256];
  __shared__ int cur[256];
  int t = threadIdx.x;
  h[t] = 0;
  __syncthreads();
  int base = blockIdx.x * 4096;
  int mys[16], myd[16];
  #pragma unroll
  for (int i = 0; i < 16; i++) {
    int j = base + t + i * 256;
    if (j < e) {
      mys[i] = src[j];
      myd[i] = dst[j];
      atomicAdd(&h[myd[i] >> 9], 1);
    } else {
      myd[i] = -1;
    }
  }
  __syncthreads();
  int cnt = h[t];
  __syncthreads();
  int gbase = 0;
  if (t < ndig && cnt > 0) gbase = atomicAdd(&gcur[t], cnt);
  h[t] = gbase;
  cur[t] = 0;
  __syncthreads();
  #pragma unroll
  for (int i = 0; i < 16; i++) {
    if (myd[i] >= 0) {
      int d = myd[i] >> 9;
      int r = atomicAdd(&cur[d], 1);
      stage[(size_t)d * DCAP + h[d] + r] = make_int2(mys[i], myd[i]);
    }
  }
}

__global__ __launch_bounds__(256) void csr_k(const int2* __restrict__ stage,
                                             const int* __restrict__ gcur,
                                             int* __restrict__ rowptr,
                                             int* __restrict__ counts,
                                             float* __restrict__ dinv,
                                             int* __restrict__ csr, int n) {
  __shared__ int hc[512];
  __shared__ int hb[512];
  __shared__ int cu[512];
  __shared__ int sc[256];
  int dg = blockIdx.x;
  int t = threadIdx.x;
  int n0 = dg * 512;
  int nloc = min(n - n0, 512);
  int e0 = dg * DCAP;
  int e1 = e0 + gcur[dg];
  hc[t] = 0; hc[t + 256] = 0;
  __syncthreads();
  for (int j = e0 + t; j < e1; j += 256) atomicAdd(&hc[stage[j].y - n0], 1);
  __syncthreads();
  int a0 = hc[2 * t], a1 = hc[2 * t + 1];
  int s = a0 + a1;
  sc[t] = s;
  __syncthreads();
  #pragma unroll
  for (int off = 1; off < 256; off <<= 1) {
    int x = sc[t] + ((t >= off) ? sc[t - off] : 0);
    __syncthreads();
    sc[t] = x;
    __syncthreads();
  }
  int excl = sc[t] - s;
  hb[2 * t] = excl;
  hb[2 * t + 1] = excl + a0;
  cu[2 * t] = 0; cu[2 * t + 1] = 0;
  __syncthreads();
  for (int i = t; i < nloc; i += 256) {
    int node = n0 + i;
    rowptr[node] = e0 + hb[i];
    counts[node] = hc[i];
    dinv[node] = rsqrtf((float)hc[i] + 1.0f);  // +1 self loop
  }
  __syncthreads();
  for (int j = e0 + t; j < e1; j += 256) {
    int2 p = stage[j];
    int li = p.y - n0;
    int r = atomicAdd(&cu[li], 1);
    csr[e0 + hb[li] + r] = p.x;
  }
}

// ================= MFMA GEMM  Y[N,64](bf16) = X[N,K] @ W[K,64] =================
// 64x64 tile, 4 waves; wave w -> rows 16w..16w+15, all 64 cols.
// LDS fragment-ordered with XOR swizzle byte^=((row&7)<<4).

template <int K, bool IN_BF16>
__global__ __launch_bounds__(256) void gemm_mfma_k(const void* __restrict__ Xv,
                                                   const float* __restrict__ W,
                                                   u16* __restrict__ Y, int n) {
  constexpr int KK = K / 32;
  constexpr int XSN = 2048 * KK;               // Xs elems (u16)
  constexpr int TOT = 4096 * KK;               // Xs + Ws
  constexpr int SMEMN = (TOT > 9216) ? TOT : 9216;  // epilogue needs 64*72*2 u16? no: 9216 u16
  __shared__ u16 smem[SMEMN];
  u16* Xs = smem;
  u16* Ws = smem + XSN;
  int t = threadIdx.x;
  int row0 = blockIdx.x * 64;

  // ---- stage W: fragment order Ws[kk][col][32 k] ----
  for (int idx = t; idx < K * 16; idx += 256) {
    int k = idx >> 4, c4 = (idx & 15) * 4;
    float4 wv = *(const float4*)(W + (size_t)k * 64 + c4);
    int kk = k >> 5, k8 = (k & 31) >> 3, kr = k & 7;
    float wa[4] = {wv.x, wv.y, wv.z, wv.w};
    #pragma unroll
    for (int j = 0; j < 4; j++) {
      int c = c4 + j;
      u32 byte = (u32)(((kk * 64 + c) * 32 + k8 * 8 + kr) * 2);
      byte ^= (u32)((c & 7) << 4);
      *(u16*)((char*)Ws + byte) = f2bf(wa[j]);
    }
  }

  // ---- stage X tile: fragment order Xs[wrow][kk][16 row][32 k] ----
  for (int idx = t; idx < 8 * K; idx += 256) {   // 64 rows * K/8 chunks
    int r = idx / (K / 8);
    int c8 = idx % (K / 8);
    int gr = row0 + r;
    u16 vals[8];
    if (gr < n) {
      if (IN_BF16) {
        *(uint4*)vals = *(const uint4*)((const u16*)Xv + (size_t)gr * K + c8 * 8);
      } else {
        const float4 x0 = *(const float4*)((const float*)Xv + (size_t)gr * K + c8 * 8);
        const float4 x1 = *(const float4*)((const float*)Xv + (size_t)gr * K + c8 * 8 + 4);
        vals[0] = f2bf(x0.x); vals[1] = f2bf(x0.y); vals[2] = f2bf(x0.z); vals[3] = f2bf(x0.w);
        vals[4] = f2bf(x1.x); vals[5] = f2bf(x1.y); vals[6] = f2bf(x1.z); vals[7] = f2bf(x1.w);
      }
    } else {
      #pragma unroll
      for (int j = 0; j < 8; j++) vals[j] = 0;
    }
    int wrow = r >> 4, row = r & 15, kk = c8 >> 2, k8 = c8 & 3;
    u32 byte = (u32)((((wrow * KK + kk) * 16 + row) * 32 + k8 * 8) * 2);
    byte ^= (u32)((row & 7) << 4);
    *(uint4*)((char*)Xs + byte) = *(uint4*)vals;
  }
  __syncthreads();

  // ---- MFMA main: hoist B frags, 1 A-read + 4 MFMA per kk ----
  int w = t >> 6, l = t & 63;
  int lrow = l & 15, lk = l >> 4;
  bf16x8 bfrag[KK][4];
  #pragma unroll
  for (int kk = 0; kk < KK; kk++) {
    #pragma unroll
    for (int cb = 0; cb < 4; cb++) {
      int col = cb * 16 + lrow;
      u32 byte = (u32)(((kk * 64 + col) * 32 + lk * 8) * 2);
      byte ^= (u32)((col & 7) << 4);
      bfrag[kk][cb] = *(bf16x8*)((char*)Ws + byte);
    }
  }
  f32x4 acc[4] = {};
  #pragma unroll
  for (int kk = 0; kk < KK; kk++) {
    u32 abyte = (u32)((((w * KK + kk) * 16 + lrow) * 32 + lk * 8) * 2);
    abyte ^= (u32)((lrow & 7) << 4);
    bf16x8 a = *(bf16x8*)((char*)Xs + abyte);
    #pragma unroll
    for (int cb = 0; cb < 4; cb++) {
      acc[cb] = __builtin_amdgcn_mfma_f32_16x16x32_bf16(a, bfrag[kk][cb], acc[cb], 0, 0, 0);
    }
  }
  __syncthreads();

  // ---- epilogue: D(col=lane&15,row=(lane>>4)*4+reg) -> LDS [64][72] -> coalesced ----
  #pragma unroll
  for (int cb = 0; cb < 4; cb++) {
    #pragma unroll
    for (int reg = 0; reg < 4; reg++) {
      int r = w * 16 + lk * 4 + reg;
      int c = cb * 16 + lrow;
      smem[r * 72 + c] = f2bf(acc[cb][reg]);
    }
  }
  __syncthreads();
  #pragma unroll
  for (int p = 0; p < 2; p++) {
    int idx = t + p * 256;
    int rr = idx >> 3, ch = idx & 7;
    int gr = row0 + rr;
    if (gr < n) {
      uint4 v = *(uint4*)&smem[rr * 72 + ch * 8];
      *(uint4*)(Y + (size_t)gr * 64 + ch * 8) = v;
    }
  }
}

// ================= edge aggregation: pipelined gather =================

__global__ __launch_bounds__(256) void gather_k(const u16* __restrict__ xw,
                                                u16* __restrict__ hout,
                                                const int* __restrict__ rowptr,
                                                const int* __restrict__ counts,
                                                const int* __restrict__ csr,
                                                const float* __restrict__ dinv,
                                                const float* __restrict__ bias, int n) {
  int idx = blockIdx.x * 256 + threadIdx.x;
  int nid = idx >> 3;
  int lane = idx & 7;
  if (nid >= n) return;
  float di = dinv[nid];
  float sc = di * di;
  float acc[8];
  {
    uint4 a = *(const uint4*)(xw + (size_t)nid * 64 + lane * 8);
    acc[0] = bflo(a.x) * sc; acc[1] = bfhi(a.x) * sc;
    acc[2] = bflo(a.y) * sc; acc[3] = bfhi(a.y) * sc;
    acc[4] = bflo(a.z) * sc; acc[5] = bfhi(a.z) * sc;
    acc[6] = bflo(a.w) * sc; acc[7] = bfhi(a.w) * sc;
  }
  int st = rowptr[nid];
  int cn = counts[nid];
  int myidx = 0;
  float dv = 0.f;
  if (lane < cn) {
    myidx = csr[st + lane];
    dv = dinv[myidx];
  }
  for (int c = 0; c < cn; c += 8) {
    int rem = cn - c;
    uint4 vv[8];
    #pragma unroll
    for (int i = 0; i < 8; i++) {
      int s = __shfl(myidx, i, 8);
      if (i < rem) {
        vv[i] = *(const uint4*)(xw + (size_t)s * 64 + lane * 8);
      } else {
        vv[i] = make_uint4(0, 0, 0, 0);
      }
    }
    float ww[8];
    float myw = dv * di;
    #pragma unroll
    for (int i = 0; i < 8; i++) ww[i] = (i < rem) ? __shfl(myw, i, 8) : 0.f;
    int nxt = 0;
    float ndv = 0.f;
    if (c + 8 < cn && lane < rem - 8) {
      nxt = csr[st + c + 8 + lane];
      ndv = dinv[nxt];
    }
    #pragma unroll
    for (int i = 0; i < 8; i++) {
      float wgt = ww[i];
      acc[0] += bflo(vv[i].x) * wgt; acc[1] += bfhi(vv[i].x) * wgt;
      acc[2] += bflo(vv[i].y) * wgt; acc[3] += bfhi(vv[i].y) * wgt;
      acc[4] += bflo(vv[i].z) * wgt; acc[5] += bfhi(vv[i].z) * wgt;
      acc[6] += bflo(vv[i].w) * wgt; acc[7] += bfhi(vv[i].w) * wgt;
    }
    myidx = nxt;
    dv = ndv;
  }
  const float4 b0 = *(const float4*)(bias + lane * 8);
  const float4 b1 = *(const float4*)(bias + lane * 8 + 4);
  acc[0] = fmaxf(acc[0] + b0.x, 0.f);
  acc[1] = fmaxf(acc[1] + b0.y, 0.f);
  acc[2] = fmaxf(acc[2] + b0.z, 0.f);
  acc[3] = fmaxf(acc[3] + b0.w, 0.f);
  acc[4] = fmaxf(acc[4] + b1.x, 0.f);
  acc[5] = fmaxf(acc[5] + b1.y, 0.f);
  acc[6] = fmaxf(acc[6] + b1.z, 0.f);
  acc[7] = fmaxf(acc[7] + b1.w, 0.f);
  uint4 o;
  o.x = ((u32)f2bf(acc[0])) | ((u32)f2bf(acc[1]) << 16);
  o.y = ((u32)f2bf(acc[2])) | ((u32)f2bf(acc[3]) << 16);
  o.z = ((u32)f2bf(acc[4])) | ((u32)f2bf(acc[5]) << 16);
  o.w = ((u32)f2bf(acc[6])) | ((u32)f2bf(acc[7]) << 16);
  *(uint4*)(hout + (size_t)nid * 64 + lane * 8) = o;
}

// ================= fused pooling + head =================

__global__ __launch_bounds__(1024) void pool_k(const u16* __restrict__ h,
                                               const int* __restrict__ batch, int n,
                                               const float* __restrict__ Wlin,
                                               const float* __restrict__ blin,
                                               float* __restrict__ xcat,
                                               float* __restrict__ outh) {
  int g = blockIdx.x;
  __shared__ int se[2];
  if (threadIdx.x < 2) {
    int target = g + (int)threadIdx.x;
    int lo = 0, hi = n;
    while (lo < hi) {
      int mid = (lo + hi) >> 1;
      if (batch[mid] < target) lo = mid + 1; else hi = mid;
    }
    se[threadIdx.x] = lo;
  }
  __syncthreads();
  int s = se[0], e = se[1];
  int lane = threadIdx.x & 63;
  int wv = threadIdx.x >> 6;
  float sum = 0.f, mx = 0.f;  // relu >= 0 -> 0-init max matches ref
  for (int nn = s + wv; nn < e; nn += 16) {
    float v = bf2f(h[(size_t)nn * 64 + lane]);
    sum += v;
    mx = fmaxf(mx, v);
  }
  __shared__ float lsum[16][64];
  __shared__ float lmax[16][64];
  lsum[wv][lane] = sum;
  lmax[wv][lane] = mx;
  __syncthreads();
  if (wv == 0) {
    #pragma unroll
    for (int i = 1; i < 16; i++) {
      sum += lsum[i][lane];
      mx = fmaxf(mx, lmax[i][lane]);
    }
    int cnt = e - s;
    float x0 = sum;
    float x1 = sum / fmaxf((float)cnt, 1.0f);
    float x2 = mx;
    xcat[g * CAT + lane]       = x0;
    xcat[g * CAT + 64 + lane]  = x1;
    xcat[g * CAT + 128 + lane] = x2;
    #pragma unroll
    for (int o = 0; o < 2; o++) {
      float p = x0 * Wlin[lane * 2 + o] +
                x1 * Wlin[(64 + lane) * 2 + o] +
                x2 * Wlin[(128 + lane) * 2 + o];
      #pragma unroll
      for (int off = 32; off > 0; off >>= 1) p += __shfl_down(p, off, 64);
      if (lane == 0) outh[g * 2 + o] = p + blin[o];
    }
  }
}

// ================= launch =================

extern "C" void kernel_launch(void* const* d_in, const int* in_sizes, int n_in,
                              void* d_out, int out_size, void* d_ws, size_t ws_size,
                              hipStream_t stream) {
  const float* x    = (const float*)d_in[0];
  const float* W1   = (const float*)d_in[1];
  const float* b1   = (const float*)d_in[2];
  const float* W2   = (const float*)d_in[3];
  const float* b2   = (const float*)d_in[4];
  const float* Wlin = (const float*)d_in[5];
  const float* blin = (const float*)d_in[6];
  const int*   ei   = (const int*)d_in[7];
  const int*   batch= (const int*)d_in[8];

  const int N = in_sizes[0] / IN_F;      // 100000
  const int E = in_sizes[7] / 2;         // 1600000
  const int* src = ei;
  const int* dst = ei + E;
  const int ndig = (N + 511) >> 9;       // 196
  const int nbE  = (E + 4095) / 4096;    // 391

  char* w = (char*)d_ws;
  auto alloc = [&](size_t bytes) {
    void* p = (void*)w;
    w += (bytes + 255) & ~(size_t)255;
    return p;
  };
  int*   rowptr = (int*)alloc((size_t)N * 4);
  int*   counts = (int*)alloc((size_t)N * 4);
  float* dinv   = (float*)alloc((size_t)N * 4);
  int*   csr    = (int*)alloc((size_t)ndig * DCAP * 4);
  int*   gcur   = (int*)alloc(256 * 4);
  u16*   bufA   = (u16*)alloc((size_t)N * 64 * 2);
  u16*   bufB   = (u16*)alloc((size_t)N * 64 * 2);
  int2*  stage  = (int2*)alloc((size_t)ndig * DCAP * 8);

  float* xcat = (float*)d_out;
  float* outh = (float*)d_out + NG * CAT;

  zeroh_k <<<1, 256, 0, stream>>>(gcur);
  stage_k <<<nbE, 256, 0, stream>>>(src, dst, E, gcur, stage, ndig);
  csr_k   <<<ndig, 256, 0, stream>>>(stage, gcur, rowptr, counts, dinv, csr, N);

  // layer 1
  gemm_mfma_k<IN_F, false> <<<(N + 63) / 64, 256, 0, stream>>>(x, W1, bufA, N);
  gather_k <<<(N * 8 + 255) / 256, 256, 0, stream>>>(bufA, bufB, rowptr, counts, csr, dinv, b1, N);

  // layer 2
  gemm_mfma_k<C1, true> <<<(N + 63) / 64, 256, 0, stream>>>(bufB, W2, bufA, N);
  gather_k <<<(N * 8 + 255) / 256, 256, 0, stream>>>(bufA, bufB, rowptr, counts, csr, dinv, b2, N);

  // fused pooling + head
  pool_k <<<NG, 1024, 0, stream>>>(bufB, batch, N, Wlin, blin, xcat, outh);
}